// Round 4
// baseline (283.503 us; speedup 1.0000x reference)
//
#include <hip/hip_runtime.h>

// loss = -sum_i  dot(s_i, im_i) / ((||s_i||+EPS) * (||im_i||+EPS))
// s, im: fp32 [N=65536, D=512].
// Round-4 change (one variable): force DEEP LOAD BATCHING. Round 2/3 compiled
// to VGPR=32 -> only ~2 float4-pairs in flight per wave (latency-serialized).
// Here: explicit A[8]/B[8] register arrays, 16 back-to-back loads per phase,
// __launch_bounds__(256,1) so regalloc may hold them all.

#define EPSV 1.1e-13f   // 1e-13 + 1e-14, matches reference

__global__ __launch_bounds__(256, 1) void cosdiag_kernel(
        const float4* __restrict__ s,
        const float4* __restrict__ im,
        float* __restrict__ part_out,   // [gridDim.x]
        int nrows) {
    const int tid   = threadIdx.x;
    const int lane  = tid & 63;
    const int wave  = tid >> 6;
    const int gwave = blockIdx.x * 4 + wave;     // 4 waves/block
    const int oct   = lane & 7;                  // which 1/8 of the row
    const int lrow  = lane >> 3;                 // row within wave's 8-row group
    const int row   = gwave * 8 + lrow;

    float ss = 0.0f, ii = 0.0f, dt = 0.0f;

    if (row < nrows) {
        const float4* __restrict__ srow = s  + (size_t)row * 128 + oct;
        const float4* __restrict__ irow = im + (size_t)row * 128 + oct;

        // Phase 1: issue 16 independent loads back-to-back, THEN consume.
        float4 A[8], B[8];
        #pragma unroll
        for (int j = 0; j < 8; ++j) A[j] = srow[(size_t)j * 8];
        #pragma unroll
        for (int j = 0; j < 8; ++j) B[j] = irow[(size_t)j * 8];
        #pragma unroll
        for (int j = 0; j < 8; ++j) {
            ss += A[j].x*A[j].x + A[j].y*A[j].y + A[j].z*A[j].z + A[j].w*A[j].w;
            ii += B[j].x*B[j].x + B[j].y*B[j].y + B[j].z*B[j].z + B[j].w*B[j].w;
            dt += A[j].x*B[j].x + A[j].y*B[j].y + A[j].z*B[j].z + A[j].w*B[j].w;
        }

        // Phase 2: second half of the row, same batching.
        #pragma unroll
        for (int j = 0; j < 8; ++j) A[j] = srow[(size_t)(j + 8) * 8];
        #pragma unroll
        for (int j = 0; j < 8; ++j) B[j] = irow[(size_t)(j + 8) * 8];
        #pragma unroll
        for (int j = 0; j < 8; ++j) {
            ss += A[j].x*A[j].x + A[j].y*A[j].y + A[j].z*A[j].z + A[j].w*A[j].w;
            ii += B[j].x*B[j].x + B[j].y*B[j].y + B[j].z*B[j].z + B[j].w*B[j].w;
            dt += A[j].x*B[j].x + A[j].y*B[j].y + A[j].z*B[j].z + A[j].w*B[j].w;
        }
    }

    // Reduce across the 8 lanes sharing a row (xor 1,2,4).
    #pragma unroll
    for (int off = 1; off <= 4; off <<= 1) {
        ss += __shfl_xor(ss, off);
        ii += __shfl_xor(ii, off);
        dt += __shfl_xor(dt, off);
    }

    float contrib = (oct == 0 && row < nrows)
                  ? dt / ((sqrtf(ss) + EPSV) * (sqrtf(ii) + EPSV))
                  : 0.0f;

    // Sum the 8 row results within the wave (xor 8,16,32).
    #pragma unroll
    for (int off = 8; off <= 32; off <<= 1) {
        contrib += __shfl_xor(contrib, off);
    }

    __shared__ float part[4];
    if (lane == 0) part[wave] = contrib;
    __syncthreads();
    if (tid == 0) {
        part_out[blockIdx.x] = part[0] + part[1] + part[2] + part[3];
    }
}

// One block: reduce nparts partials -> out[0] = -sum.
__global__ __launch_bounds__(256) void reduce_kernel(
        const float* __restrict__ parts, float* __restrict__ out, int nparts) {
    const int tid = threadIdx.x;
    float v = 0.0f;
    for (int i = tid; i < nparts; i += 256) v += parts[i];

    #pragma unroll
    for (int off = 32; off > 0; off >>= 1) v += __shfl_xor(v, off);

    __shared__ float wsum[4];
    if ((tid & 63) == 0) wsum[tid >> 6] = v;
    __syncthreads();
    if (tid == 0) out[0] = -(wsum[0] + wsum[1] + wsum[2] + wsum[3]);
}

extern "C" void kernel_launch(void* const* d_in, const int* in_sizes, int n_in,
                              void* d_out, int out_size, void* d_ws, size_t ws_size,
                              hipStream_t stream) {
    const float* s  = (const float*)d_in[0];
    const float* im = (const float*)d_in[1];
    // d_in[2] = temp (unused by the loss)
    float* out   = (float*)d_out;
    float* parts = (float*)d_ws;         // 2048 floats = 8 KB scratch

    const int D = 512;
    const int nrows = in_sizes[0] / D;   // 65536

    // 8 threads/row, 256 threads/block -> 32 rows/block.
    const int rows_per_block = 32;
    int grid = (nrows + rows_per_block - 1) / rows_per_block;   // 2048

    cosdiag_kernel<<<grid, 256, 0, stream>>>(
        (const float4*)s, (const float4*)im, parts, nrows);

    reduce_kernel<<<1, 256, 0, stream>>>(parts, out, grid);
}

// Round 5
// 276.581 us; speedup vs baseline: 1.0250x; 1.0250x over previous
//
#include <hip/hip_runtime.h>

// loss = -sum_i  dot(s_i, im_i) / ((||s_i||+EPS) * (||im_i||+EPS))
// s, im: fp32 [N=65536, D=512].
// Round-5 change (one variable): FORCE 32 loads in flight per thread.
// Round 4's A[8]/B[8] batch was re-serialized by the scheduler (VGPR=36).
// Here: all 32 loads issued back-to-back, then sched_barrier(0) pins them
// before any consume. Expect VGPR ~150 (occupancy ~3 waves/SIMD).
// If duration stays ~100us with VGPR high, the 2.58 TB/s service-rate cap
// is structural (fabric/dirty-line), not a concurrency shortfall.

#define EPSV 1.1e-13f   // 1e-13 + 1e-14, matches reference

__global__ __launch_bounds__(256, 1) void cosdiag_kernel(
        const float4* __restrict__ s,
        const float4* __restrict__ im,
        float* __restrict__ part_out,   // [gridDim.x]
        int nrows) {
    const int tid   = threadIdx.x;
    const int lane  = tid & 63;
    const int wave  = tid >> 6;
    const int gwave = blockIdx.x * 4 + wave;     // 4 waves/block
    const int oct   = lane & 7;                  // which 1/8 of the row
    const int lrow  = lane >> 3;                 // row within wave's 8-row group
    const int row   = gwave * 8 + lrow;          // grid is exact: row < nrows always

    const float4* __restrict__ srow = s  + (size_t)row * 128 + oct;
    const float4* __restrict__ irow = im + (size_t)row * 128 + oct;

    // Issue ALL 32 independent loads, interleaved so consume order (A0,B0),
    // (A1,B1)... drains vmcnt incrementally (first use waits vmcnt(30)).
    float4 A[16], B[16];
    #pragma unroll
    for (int j = 0; j < 16; ++j) {
        A[j] = srow[(size_t)j * 8];
        B[j] = irow[(size_t)j * 8];
    }
    // Pin: no consume may be hoisted above, no load may be sunk below.
    __builtin_amdgcn_sched_barrier(0);

    float ss = 0.0f, ii = 0.0f, dt = 0.0f;
    #pragma unroll
    for (int j = 0; j < 16; ++j) {
        ss += A[j].x*A[j].x + A[j].y*A[j].y + A[j].z*A[j].z + A[j].w*A[j].w;
        ii += B[j].x*B[j].x + B[j].y*B[j].y + B[j].z*B[j].z + B[j].w*B[j].w;
        dt += A[j].x*B[j].x + A[j].y*B[j].y + A[j].z*B[j].z + A[j].w*B[j].w;
    }

    // Reduce across the 8 lanes sharing a row (xor 1,2,4).
    #pragma unroll
    for (int off = 1; off <= 4; off <<= 1) {
        ss += __shfl_xor(ss, off);
        ii += __shfl_xor(ii, off);
        dt += __shfl_xor(dt, off);
    }

    float contrib = (oct == 0)
                  ? dt / ((sqrtf(ss) + EPSV) * (sqrtf(ii) + EPSV))
                  : 0.0f;

    // Sum the 8 row results within the wave (xor 8,16,32).
    #pragma unroll
    for (int off = 8; off <= 32; off <<= 1) {
        contrib += __shfl_xor(contrib, off);
    }

    __shared__ float part[4];
    if (lane == 0) part[wave] = contrib;
    __syncthreads();
    if (tid == 0) {
        part_out[blockIdx.x] = part[0] + part[1] + part[2] + part[3];
    }
}

// One block: reduce nparts partials -> out[0] = -sum.
__global__ __launch_bounds__(256) void reduce_kernel(
        const float* __restrict__ parts, float* __restrict__ out, int nparts) {
    const int tid = threadIdx.x;
    float v = 0.0f;
    for (int i = tid; i < nparts; i += 256) v += parts[i];

    #pragma unroll
    for (int off = 32; off > 0; off >>= 1) v += __shfl_xor(v, off);

    __shared__ float wsum[4];
    if ((tid & 63) == 0) wsum[tid >> 6] = v;
    __syncthreads();
    if (tid == 0) out[0] = -(wsum[0] + wsum[1] + wsum[2] + wsum[3]);
}

extern "C" void kernel_launch(void* const* d_in, const int* in_sizes, int n_in,
                              void* d_out, int out_size, void* d_ws, size_t ws_size,
                              hipStream_t stream) {
    const float* s  = (const float*)d_in[0];
    const float* im = (const float*)d_in[1];
    // d_in[2] = temp (unused by the loss)
    float* out   = (float*)d_out;
    float* parts = (float*)d_ws;         // 2048 floats = 8 KB scratch

    const int D = 512;
    const int nrows = in_sizes[0] / D;   // 65536

    // 8 threads/row, 256 threads/block -> 32 rows/block -> grid 2048 (exact).
    const int rows_per_block = 32;
    int grid = (nrows + rows_per_block - 1) / rows_per_block;   // 2048

    cosdiag_kernel<<<grid, 256, 0, stream>>>(
        (const float4*)s, (const float4*)im, parts, nrows);

    reduce_kernel<<<1, 256, 0, stream>>>(parts, out, grid);
}